// Round 1
// baseline (190.100 us; speedup 1.0000x reference)
//
#include <hip/hip_runtime.h>
#include <hip/hip_bf16.h>
#include <stdint.h>

#define BM 128
#define BN 128
#define BK 64

typedef __attribute__((ext_vector_type(4))) float f32x4;
typedef __attribute__((ext_vector_type(8))) short bf16x8;

__device__ __forceinline__ unsigned short f2bf(float f) {
  unsigned int u = __float_as_uint(f);
  u += 0x7FFFu + ((u >> 16) & 1u);   // round-to-nearest-even
  return (unsigned short)(u >> 16);
}

// Kernel 1: per-row normalize (fp32), cast to bf16; diag[i] = cos(a_i, b_i) in fp32.
__global__ __launch_bounds__(64) void norm_kernel(
    const float* __restrict__ a, const float* __restrict__ b,
    unsigned short* __restrict__ an, unsigned short* __restrict__ bn,
    float* __restrict__ diag, int D) {
  const int row = blockIdx.x;
  const int l = threadIdx.x;
  const float4* ar = (const float4*)(a + (size_t)row * D);
  const float4* br = (const float4*)(b + (size_t)row * D);
  const int nd4 = D >> 2;
  float ssa = 0.f, ssb = 0.f, dot = 0.f;
  for (int c = l; c < nd4; c += 64) {
    float4 av = ar[c], bv = br[c];
    ssa += av.x*av.x + av.y*av.y + av.z*av.z + av.w*av.w;
    ssb += bv.x*bv.x + bv.y*bv.y + bv.z*bv.z + bv.w*bv.w;
    dot += av.x*bv.x + av.y*bv.y + av.z*bv.z + av.w*bv.w;
  }
  for (int off = 1; off < 64; off <<= 1) {
    ssa += __shfl_xor(ssa, off, 64);
    ssb += __shfl_xor(ssb, off, 64);
    dot += __shfl_xor(dot, off, 64);
  }
  const float inva = 1.0f / sqrtf(ssa);
  const float invb = 1.0f / sqrtf(ssb);
  if (l == 0) diag[row] = dot * inva * invb;
  ushort4* anr = (ushort4*)(an + (size_t)row * D);
  ushort4* bnr = (ushort4*)(bn + (size_t)row * D);
  for (int c = l; c < nd4; c += 64) {
    float4 av = ar[c], bv = br[c];
    ushort4 ap, bp;
    ap.x = f2bf(av.x * inva); ap.y = f2bf(av.y * inva);
    ap.z = f2bf(av.z * inva); ap.w = f2bf(av.w * inva);
    bp.x = f2bf(bv.x * invb); bp.y = f2bf(bv.y * invb);
    bp.z = f2bf(bv.z * invb); bp.w = f2bf(bv.w * invb);
    anr[c] = ap; bnr[c] = bp;
  }
}

// Kernel 2: 128x128 bf16 MFMA tile GEMM; fused epilogue computes per-tile
// masked row-max (dir1) and col-max (dir2) of the scores; writes partials.
// row_part[tj*B + i], col_part[ti*B + j].
__global__ __launch_bounds__(256) void gemm_max_kernel(
    const unsigned short* __restrict__ an, const unsigned short* __restrict__ bn,
    const int* __restrict__ labels, const float* __restrict__ diag,
    float* __restrict__ row_part, float* __restrict__ col_part,
    int B, int D) {
  __shared__ __align__(16) unsigned short sA[BM * BK];
  __shared__ __align__(16) unsigned short sB[BN * BK];
  __shared__ float lds_row[2][BM];
  __shared__ float lds_col[2][BN];

  const int tid  = threadIdx.x;
  const int lane = tid & 63;
  const int w    = tid >> 6;        // wave 0..3
  const int wm   = w >> 1;          // wave row-half
  const int wn   = w & 1;           // wave col-half
  const int ti   = blockIdx.y, tj = blockIdx.x;

  f32x4 acc[4][4];
  #pragma unroll
  for (int mt = 0; mt < 4; ++mt)
    #pragma unroll
    for (int nt = 0; nt < 4; ++nt)
      acc[mt][nt] = (f32x4){0.f, 0.f, 0.f, 0.f};

  // staging address decomposition: wave handles 4 chunks of (8 rows x 64 cols)
  const int lr = lane >> 3;          // 0..7: row within 8-row chunk
  const int lc = (lane & 7) * 8;     // 0..56: element col offset (16B per lane)
  const unsigned short* gA0 = an + ((size_t)(ti * BM + w * 32 + lr)) * D + lc;
  const unsigned short* gB0 = bn + ((size_t)(tj * BN + w * 32 + lr)) * D + lc;

  const int fr = lane & 15;          // fragment m/n index
  const int fk = (lane >> 4) * 8;    // fragment k offset

  for (int kb = 0; kb < D; kb += BK) {
    #pragma unroll
    for (int c = 0; c < 4; ++c) {
      const unsigned short* ga = gA0 + (size_t)(c * 8) * D + kb;
      const unsigned short* gb = gB0 + (size_t)(c * 8) * D + kb;
      unsigned short* la = sA + (w * 32 + c * 8 + lr) * BK + lc;
      unsigned short* lb = sB + (w * 32 + c * 8 + lr) * BK + lc;
      __builtin_amdgcn_global_load_lds(
          (const __attribute__((address_space(1))) void*)ga,
          (__attribute__((address_space(3))) void*)la, 16, 0, 0);
      __builtin_amdgcn_global_load_lds(
          (const __attribute__((address_space(1))) void*)gb,
          (__attribute__((address_space(3))) void*)lb, 16, 0, 0);
    }
    __syncthreads();
    #pragma unroll
    for (int kk = 0; kk < 2; ++kk) {
      bf16x8 afrag[4], bfrag[4];
      #pragma unroll
      for (int t = 0; t < 4; ++t) {
        afrag[t] = *(const bf16x8*)(sA + (wm * 64 + t * 16 + fr) * BK + kk * 32 + fk);
        bfrag[t] = *(const bf16x8*)(sB + (wn * 64 + t * 16 + fr) * BK + kk * 32 + fk);
      }
      #pragma unroll
      for (int mt = 0; mt < 4; ++mt)
        #pragma unroll
        for (int nt = 0; nt < 4; ++nt)
          acc[mt][nt] = __builtin_amdgcn_mfma_f32_16x16x32_bf16(
              afrag[mt], bfrag[nt], acc[mt][nt], 0, 0, 0);
    }
    __syncthreads();
  }

  // Epilogue: masked max. C/D layout: col = lane&15, row = (lane>>4)*4 + reg.
  const int lrow = lane >> 4;   // quad 0..3
  const int lcol = lane & 15;

  int   labc[4];
  float dc[4];
  #pragma unroll
  for (int nt = 0; nt < 4; ++nt) {
    const int j = tj * BN + wn * 64 + nt * 16 + lcol;
    labc[nt] = labels[j];
    dc[nt]   = diag[j];
  }

  float cmax[4] = {-1e9f, -1e9f, -1e9f, -1e9f};
  #pragma unroll
  for (int mt = 0; mt < 4; ++mt) {
    #pragma unroll
    for (int r = 0; r < 4; ++r) {
      const int i = ti * BM + wm * 64 + mt * 16 + lrow * 4 + r;
      const int li = labels[i];
      const float di = diag[i];
      float rmax = -1e9f;
      #pragma unroll
      for (int nt = 0; nt < 4; ++nt) {
        const float v = acc[mt][nt][r];
        const bool neq = (li != labc[nt]);
        if (neq && (v + 0.2f > di))     rmax     = fmaxf(rmax, v);
        if (neq && (v + 0.2f > dc[nt])) cmax[nt] = fmaxf(cmax[nt], v);
      }
      #pragma unroll
      for (int off = 1; off < 16; off <<= 1)
        rmax = fmaxf(rmax, __shfl_xor(rmax, off, 64));
      if (lcol == 0) lds_row[wn][wm * 64 + mt * 16 + lrow * 4 + r] = rmax;
    }
  }
  #pragma unroll
  for (int nt = 0; nt < 4; ++nt) {
    float c = cmax[nt];
    c = fmaxf(c, __shfl_xor(c, 16, 64));
    c = fmaxf(c, __shfl_xor(c, 32, 64));
    if (lrow == 0) lds_col[wm][wn * 64 + nt * 16 + lcol] = c;
  }
  __syncthreads();
  if (tid < BM) {
    const float r = fmaxf(lds_row[0][tid], lds_row[1][tid]);
    row_part[(size_t)tj * B + ti * BM + tid] = r;
  } else if (tid < BM + BN) {
    const int t2 = tid - BM;
    const float c = fmaxf(lds_col[0][t2], lds_col[1][t2]);
    col_part[(size_t)ti * B + tj * BN + t2] = c;
  }
}

// Kernel 3: per virtual row v in [0,2B): reduce partials -> neg_max, compute
// row loss, block-reduce, write per-block partial sum.
__global__ __launch_bounds__(256) void finalize_kernel(
    const float* __restrict__ row_part, const float* __restrict__ col_part,
    const float* __restrict__ diag, int B, int T, float* __restrict__ partials) {
  const int v = blockIdx.x * 256 + threadIdx.x;
  float loss = 0.f;
  const int i = (v < B) ? v : v - B;
  const float* part = (v < B) ? row_part : col_part;
  float m = -1e9f;
  for (int t = 0; t < T; ++t) m = fmaxf(m, part[(size_t)t * B + i]);
  const float d = diag[i];
  const bool valid = (d < 1.0f - 1e-5f) && (m > -1e8f);
  if (valid) {
    const float pl = fmaxf(0.2f * d * d - 0.7f * d + 0.5f, 0.f);
    const float nl = fmaxf(0.9f * m * m - 0.4f * m + 0.03f, 0.f);
    loss = pl + nl;
  }
  for (int off = 1; off < 64; off <<= 1) loss += __shfl_xor(loss, off, 64);
  __shared__ float ssum[4];
  const int wv = threadIdx.x >> 6;
  if ((threadIdx.x & 63) == 0) ssum[wv] = loss;
  __syncthreads();
  if (threadIdx.x == 0)
    partials[blockIdx.x] = ssum[0] + ssum[1] + ssum[2] + ssum[3];
}

// Kernel 4: double-precision final sum of block partials, / B.
__global__ __launch_bounds__(64) void reduce_kernel(
    const float* __restrict__ partials, int n, int B, float* __restrict__ out) {
  const int l = threadIdx.x;
  double s = 0.0;
  for (int c = l; c < n; c += 64) s += (double)partials[c];
  for (int off = 1; off < 64; off <<= 1) s += __shfl_xor(s, off, 64);
  if (l == 0) out[0] = (float)(s / (double)B);
}

extern "C" void kernel_launch(void* const* d_in, const int* in_sizes, int n_in,
                              void* d_out, int out_size, void* d_ws, size_t ws_size,
                              hipStream_t stream) {
  const float* a      = (const float*)d_in[0];
  const float* b      = (const float*)d_in[1];
  const int*   labels = (const int*)d_in[2];
  const int B = in_sizes[2];
  const int D = in_sizes[0] / B;
  const int T = B / BM;                 // partial slots per direction

  char* ws = (char*)d_ws;
  unsigned short* an = (unsigned short*)ws;                         // B*D*2 bytes
  unsigned short* bn = (unsigned short*)(ws + (size_t)B * D * 2);   // B*D*2 bytes
  float* diag     = (float*)(ws + (size_t)B * D * 4);               // B*4
  float* row_part = diag + B;                                       // T*B*4
  float* col_part = row_part + (size_t)T * B;                       // T*B*4
  float* partials = col_part + (size_t)T * B;                       // (2B/256)*4

  norm_kernel<<<B, 64, 0, stream>>>(a, b, an, bn, diag, D);

  dim3 grid(B / BN, B / BM);
  gemm_max_kernel<<<grid, 256, 0, stream>>>(an, bn, labels, diag,
                                            row_part, col_part, B, D);

  const int nfin = (2 * B) / 256;
  finalize_kernel<<<nfin, 256, 0, stream>>>(row_part, col_part, diag, B, T, partials);
  reduce_kernel<<<1, 64, 0, stream>>>(partials, nfin, B, (float*)d_out);
}

// Round 2
// 156.581 us; speedup vs baseline: 1.2141x; 1.2141x over previous
//
#include <hip/hip_runtime.h>
#include <stdint.h>

#define BM 128
#define BN 128
#define BK 64

typedef __attribute__((ext_vector_type(4))) float f32x4;
typedef __attribute__((ext_vector_type(8))) short bf16x8;

__device__ __forceinline__ unsigned short f2bf(float f) {
  unsigned int u = __float_as_uint(f);
  u += 0x7FFFu + ((u >> 16) & 1u);   // round-to-nearest-even
  return (unsigned short)(u >> 16);
}

// Kernel 1: per-row normalize (fp32), cast to bf16; diag[i] = cos(a_i, b_i) in fp32.
// One wave per row, 4 rows per block.
__global__ __launch_bounds__(256) void norm_kernel(
    const float* __restrict__ a, const float* __restrict__ b,
    unsigned short* __restrict__ an, unsigned short* __restrict__ bn,
    float* __restrict__ diag, int D) {
  const int row = blockIdx.x * 4 + (threadIdx.x >> 6);
  const int l = threadIdx.x & 63;
  const float4* ar = (const float4*)(a + (size_t)row * D);
  const float4* br = (const float4*)(b + (size_t)row * D);
  const int nd4 = D >> 2;
  float ssa = 0.f, ssb = 0.f, dot = 0.f;
  for (int c = l; c < nd4; c += 64) {
    float4 av = ar[c], bv = br[c];
    ssa += av.x*av.x + av.y*av.y + av.z*av.z + av.w*av.w;
    ssb += bv.x*bv.x + bv.y*bv.y + bv.z*bv.z + bv.w*bv.w;
    dot += av.x*bv.x + av.y*bv.y + av.z*bv.z + av.w*bv.w;
  }
  for (int off = 1; off < 64; off <<= 1) {
    ssa += __shfl_xor(ssa, off, 64);
    ssb += __shfl_xor(ssb, off, 64);
    dot += __shfl_xor(dot, off, 64);
  }
  const float inva = 1.0f / sqrtf(ssa);
  const float invb = 1.0f / sqrtf(ssb);
  if (l == 0) diag[row] = dot * inva * invb;
  ushort4* anr = (ushort4*)(an + (size_t)row * D);
  ushort4* bnr = (ushort4*)(bn + (size_t)row * D);
  for (int c = l; c < nd4; c += 64) {
    float4 av = ar[c], bv = br[c];
    ushort4 ap, bp;
    ap.x = f2bf(av.x * inva); ap.y = f2bf(av.y * inva);
    ap.z = f2bf(av.z * inva); ap.w = f2bf(av.w * inva);
    bp.x = f2bf(bv.x * invb); bp.y = f2bf(bv.y * invb);
    bp.z = f2bf(bv.z * invb); bp.w = f2bf(bv.w * invb);
    anr[c] = ap; bnr[c] = bp;
  }
}

// Kernel 2: 128x128 bf16 MFMA tile GEMM with XOR-swizzled LDS (kills the
// 16-way bank conflict: row stride 128B aliases all rows onto the same banks,
// so chunk g of row r is stored at LDS chunk g ^ (r&7); the swizzle is applied
// on the GLOBAL source address since global_load_lds's LDS side must stay
// lane-contiguous). Epilogue computes plain label-masked row/col max only
// (threshold vs diag moved to finalize — max over {v>t} == max if max>t).
__global__ __launch_bounds__(256) void gemm_max_kernel(
    const unsigned short* __restrict__ an, const unsigned short* __restrict__ bn,
    const int* __restrict__ labels,
    float* __restrict__ row_part, float* __restrict__ col_part,
    int B, int D) {
  __shared__ __align__(16) unsigned short sA[BM * BK];
  __shared__ __align__(16) unsigned short sB[BN * BK];
  __shared__ float lds_row[2][BM];
  __shared__ float lds_col[2][BN];

  const int tid  = threadIdx.x;
  const int lane = tid & 63;
  const int w    = tid >> 6;        // wave 0..3
  const int wm   = w >> 1;          // wave row-half
  const int wn   = w & 1;           // wave col-half
  const int ti   = blockIdx.y, tj = blockIdx.x;

  f32x4 acc[4][4];
  #pragma unroll
  for (int mt = 0; mt < 4; ++mt)
    #pragma unroll
    for (int nt = 0; nt < 4; ++nt)
      acc[mt][nt] = (f32x4){0.f, 0.f, 0.f, 0.f};

  // Staging: wave covers 4 chunks of (8 rows x 64 cols); lane -> row lr,
  // 16B chunk (lane&7), fetched from swizzled global chunk (lane&7)^lr.
  const int lr = lane >> 3;                   // 0..7
  const int sw = ((lane & 7) ^ lr) * 8;       // swizzled k-chunk offset (shorts)
  const unsigned short* gA0 = an + ((size_t)(ti * BM + w * 32 + lr)) * D + sw;
  const unsigned short* gB0 = bn + ((size_t)(tj * BN + w * 32 + lr)) * D + sw;

  const int fr = lane & 15;          // fragment m/n index
  const int hi = lane >> 4;          // k-quad
  const int fsw = fr & 7;            // row-parity for deswizzle

  for (int kb = 0; kb < D; kb += BK) {
    #pragma unroll
    for (int c = 0; c < 4; ++c) {
      const unsigned short* ga = gA0 + (size_t)(c * 8) * D + kb;
      const unsigned short* gb = gB0 + (size_t)(c * 8) * D + kb;
      unsigned short* la = sA + (w * 32 + c * 8) * BK + lane * 8;
      unsigned short* lb = sB + (w * 32 + c * 8) * BK + lane * 8;
      __builtin_amdgcn_global_load_lds(
          (const __attribute__((address_space(1))) void*)ga,
          (__attribute__((address_space(3))) void*)la, 16, 0, 0);
      __builtin_amdgcn_global_load_lds(
          (const __attribute__((address_space(1))) void*)gb,
          (__attribute__((address_space(3))) void*)lb, 16, 0, 0);
    }
    __syncthreads();
    #pragma unroll
    for (int kk = 0; kk < 2; ++kk) {
      bf16x8 afrag[4], bfrag[4];
      #pragma unroll
      for (int t = 0; t < 4; ++t) {
        const int ck = ((kk * 4 + hi) ^ fsw) * 8;   // deswizzled chunk offset
        afrag[t] = *(const bf16x8*)(sA + (wm * 64 + t * 16 + fr) * BK + ck);
        bfrag[t] = *(const bf16x8*)(sB + (wn * 64 + t * 16 + fr) * BK + ck);
      }
      #pragma unroll
      for (int mt = 0; mt < 4; ++mt)
        #pragma unroll
        for (int nt = 0; nt < 4; ++nt)
          acc[mt][nt] = __builtin_amdgcn_mfma_f32_16x16x32_bf16(
              afrag[mt], bfrag[nt], acc[mt][nt], 0, 0, 0);
    }
    __syncthreads();
  }

  // Epilogue: plain label-masked max. C/D layout: col = lane&15, row = (lane>>4)*4 + reg.
  const int lrow = lane >> 4;   // quad 0..3
  const int lcol = lane & 15;

  int labc[4];
  #pragma unroll
  for (int nt = 0; nt < 4; ++nt)
    labc[nt] = labels[tj * BN + wn * 64 + nt * 16 + lcol];

  float cmax[4] = {-1e9f, -1e9f, -1e9f, -1e9f};
  #pragma unroll
  for (int mt = 0; mt < 4; ++mt) {
    #pragma unroll
    for (int r = 0; r < 4; ++r) {
      const int i = ti * BM + wm * 64 + mt * 16 + lrow * 4 + r;
      const int li = labels[i];
      float rmax = -1e9f;
      #pragma unroll
      for (int nt = 0; nt < 4; ++nt) {
        const float v = acc[mt][nt][r];
        const float vm = (li != labc[nt]) ? v : -1e9f;
        rmax = fmaxf(rmax, vm);
        cmax[nt] = fmaxf(cmax[nt], vm);
      }
      #pragma unroll
      for (int off = 1; off < 16; off <<= 1)
        rmax = fmaxf(rmax, __shfl_xor(rmax, off, 64));
      if (lcol == 0) lds_row[wn][wm * 64 + mt * 16 + lrow * 4 + r] = rmax;
    }
  }
  #pragma unroll
  for (int nt = 0; nt < 4; ++nt) {
    float c = cmax[nt];
    c = fmaxf(c, __shfl_xor(c, 16, 64));
    c = fmaxf(c, __shfl_xor(c, 32, 64));
    if (lrow == 0) lds_col[wm][wn * 64 + nt * 16 + lcol] = c;
  }
  __syncthreads();
  if (tid < BM) {
    const float r = fmaxf(lds_row[0][tid], lds_row[1][tid]);
    row_part[(size_t)tj * B + ti * BM + tid] = r;
  } else if (tid < BM + BN) {
    const int t2 = tid - BM;
    const float c = fmaxf(lds_col[0][t2], lds_col[1][t2]);
    col_part[(size_t)ti * B + tj * BN + t2] = c;
  }
}

// Kernel 3: reduce per-tile maxes -> neg max M; apply hard-negative threshold
// (M + margin > diag) and pos_valid; per-row loss; block partial sum.
__global__ __launch_bounds__(256) void finalize_kernel(
    const float* __restrict__ row_part, const float* __restrict__ col_part,
    const float* __restrict__ diag, int B, int T, float* __restrict__ partials) {
  const int v = blockIdx.x * 256 + threadIdx.x;
  float loss = 0.f;
  const int i = (v < B) ? v : v - B;
  const float* part = (v < B) ? row_part : col_part;
  float m = -1e9f;
  for (int t = 0; t < T; ++t) m = fmaxf(m, part[(size_t)t * B + i]);
  const float d = diag[i];
  const bool valid = (d < 1.0f - 1e-5f) && (m + 0.2f > d);
  if (valid) {
    const float pl = fmaxf(0.2f * d * d - 0.7f * d + 0.5f, 0.f);
    const float nl = fmaxf(0.9f * m * m - 0.4f * m + 0.03f, 0.f);
    loss = pl + nl;
  }
  for (int off = 1; off < 64; off <<= 1) loss += __shfl_xor(loss, off, 64);
  __shared__ float ssum[4];
  const int wv = threadIdx.x >> 6;
  if ((threadIdx.x & 63) == 0) ssum[wv] = loss;
  __syncthreads();
  if (threadIdx.x == 0)
    partials[blockIdx.x] = ssum[0] + ssum[1] + ssum[2] + ssum[3];
}

// Kernel 4: double-precision final sum of block partials, / B.
__global__ __launch_bounds__(64) void reduce_kernel(
    const float* __restrict__ partials, int n, int B, float* __restrict__ out) {
  const int l = threadIdx.x;
  double s = 0.0;
  for (int c = l; c < n; c += 64) s += (double)partials[c];
  for (int off = 1; off < 64; off <<= 1) s += __shfl_xor(s, off, 64);
  if (l == 0) out[0] = (float)(s / (double)B);
}

extern "C" void kernel_launch(void* const* d_in, const int* in_sizes, int n_in,
                              void* d_out, int out_size, void* d_ws, size_t ws_size,
                              hipStream_t stream) {
  const float* a      = (const float*)d_in[0];
  const float* b      = (const float*)d_in[1];
  const int*   labels = (const int*)d_in[2];
  const int B = in_sizes[2];
  const int D = in_sizes[0] / B;
  const int T = B / BM;                 // partial slots per direction

  char* ws = (char*)d_ws;
  unsigned short* an = (unsigned short*)ws;                         // B*D*2 bytes
  unsigned short* bn = (unsigned short*)(ws + (size_t)B * D * 2);   // B*D*2 bytes
  float* diag     = (float*)(ws + (size_t)B * D * 4);               // B*4
  float* row_part = diag + B;                                       // T*B*4
  float* col_part = row_part + (size_t)T * B;                       // T*B*4
  float* partials = col_part + (size_t)T * B;                       // (2B/256)*4

  norm_kernel<<<B / 4, 256, 0, stream>>>(a, b, an, bn, diag, D);

  dim3 grid(B / BN, B / BM);
  gemm_max_kernel<<<grid, 256, 0, stream>>>(an, bn, labels,
                                            row_part, col_part, B, D);

  const int nfin = (2 * B) / 256;
  finalize_kernel<<<nfin, 256, 0, stream>>>(row_part, col_part, diag, B, T, partials);
  reduce_kernel<<<1, 64, 0, stream>>>(partials, nfin, B, (float*)d_out);
}